// Round 12
// baseline (179.654 us; speedup 1.0000x reference)
//
#include <hip/hip_runtime.h>
#include <hip/hip_bf16.h>

// LSTM cell fused kernel for MI355X (gfx950) — round 12:
// A-conversion FUSED into the GEMM (reg-staged cast-on-stage); convA removed.
// gemm schedule = round-4 verbatim otherwise (best measured).
//
// stacked = [x|prevh] @ [Wx;Wh] + bx -> gates -> nexth, nextc
// GEMM: M=8192, N=4096 (4 gates x 1024 states), K=2048, bf16 16x16x32 MFMA.
//
// A staging (new): region 1 issues 8 x global_load_dwordx4 of fp32 x/prevh
// (per thread: rows {p*128 + w*8 + lane>>3} + {.. +64}, cols tt*64 + scol,
// scol = inverse-swizzled granule — SAME source element the old gload_lds
// pulled); region 2 after vmcnt(4) converts (32 scalar cvt) and ds_writes
// 4 x b128 to the SAME linear dest bytes. LDS image identical to r4 ->
// read-side swizzle unchanged, 0 bank conflicts.
// vmcnt in region 2: queue = SB(t+1)[4] + A_fp32(t+1)[8] + SB(t+2)[4] = 16;
// vmcnt(4) completes SB(t+1)+A (replaces r4's guarantee). ds_writes drain
// via lgkm(0) under MFMA burst 2, before end barrier. WAR: write slot
// parity (t+1) != read slot parity (t); old content read-complete at
// end-bar(t-1). Safe.
//
// ws layout: Wt_bf16 [4096 perm][2048] (16MB) only.

#define BATCH   8192
#define SDIM    1024
#define KDIM    2048
#define NT      32      // K-tiles of 64

typedef __attribute__((ext_vector_type(8))) short s16x8;
typedef __attribute__((ext_vector_type(4))) float f32x4;

__device__ __forceinline__ void gload16(const void* g, void* l) {
    __builtin_amdgcn_global_load_lds((const __attribute__((address_space(1))) void*)g,
                                     (__attribute__((address_space(3))) void*)l,
                                     16, 0, 0);
}

__device__ __forceinline__ float fast_sigmoid(float x) {
    return 1.0f / (1.0f + __expf(-x));
}
__device__ __forceinline__ float fast_tanh(float v) {
    float a = fabsf(v);
    float e = __expf(-2.0f * a);
    float t = (1.0f - e) / (1.0f + e);
    return copysignf(t, v);
}

__device__ __forceinline__ s16x8 cvt8(float4 a, float4 b) {
    union { __hip_bfloat16 h[8]; s16x8 v; } u;
    u.h[0] = __float2bfloat16(a.x); u.h[1] = __float2bfloat16(a.y);
    u.h[2] = __float2bfloat16(a.z); u.h[3] = __float2bfloat16(a.w);
    u.h[4] = __float2bfloat16(b.x); u.h[5] = __float2bfloat16(b.y);
    u.h[6] = __float2bfloat16(b.z); u.h[7] = __float2bfloat16(b.w);
    return u.v;
}

// ---- convW: transpose + cast + gate-permute via 64x64 LDS tile (r11) ------
// Wt[np][k] = W[k][n], np = (s>>4)*64 + g*16 + (s&15)
__global__ __launch_bounds__(256) void convW(
    const float* __restrict__ Wx, const float* __restrict__ Wh,
    __hip_bfloat16* __restrict__ Wt)
{
    __shared__ float tile[64][68];
    const int wb = blockIdx.x;          // 0..2047
    const int kt = wb & 31;             // 32 k-tiles of 64
    const int nt = wb >> 5;             // 64 n-tiles of 64
    const int k0 = kt * 64, n0 = nt * 64;
    const int t  = threadIdx.x;

    {
        int r = t >> 2;
        int c = (t & 3) * 16;
        int k = k0 + r;
        const float* src = (k < 1024) ? (Wx + (size_t)k * 4096 + n0 + c)
                                      : (Wh + (size_t)(k - 1024) * 4096 + n0 + c);
#pragma unroll
        for (int jq = 0; jq < 4; ++jq)
            *(float4*)&tile[r][c + jq * 4] = *(const float4*)(src + jq * 4);
    }
    __syncthreads();

#pragma unroll
    for (int it = 0; it < 2; ++it) {
        int item = t + it * 256;
        int oct  = item >> 6;
        int nl   = item & 63;
        int n    = n0 + nl;
        int s    = n & 1023, g = n >> 10;
        int np   = (s >> 4) * 64 + g * 16 + (s & 15);
        union { __hip_bfloat16 b[8]; s16x8 v; } u;
#pragma unroll
        for (int e = 0; e < 8; ++e)
            u.b[e] = __float2bfloat16(tile[oct * 8 + e][nl]);
        *(s16x8*)(Wt + (size_t)np * 2048 + k0 + oct * 8) = u.v;
    }
}

// ---------------- fused GEMM + A-cast + gates -------------------------------
__global__ __launch_bounds__(512, 2) void lstm_gemm(
    const float* __restrict__ x,             // [8192][1024] fp32
    const float* __restrict__ prevh,         // [8192][1024] fp32
    const __hip_bfloat16* __restrict__ Wt,   // [4096 perm][2048]
    const float* __restrict__ bx,            // [4096]
    const float* __restrict__ prevc,         // [8192][1024]
    float* __restrict__ outh,
    float* __restrict__ outc)
{
    __shared__ __align__(16) char lds[131072];

    const int tid  = threadIdx.x;
    const int lane = tid & 63;
    const int w    = tid >> 6;   // 0..7
    const int wr   = w >> 2;     // 0..1  A-half
    const int wc   = w & 3;      // 0..3  N quarter; B-half = wc>>1
    const int l15  = lane & 15;

    const int bid = blockIdx.x;
    const int xcd = bid & 7, j = bid >> 3;
    const int mt = (xcd >> 1) * 8 + (j & 7);     // 0..31
    const int nt = (xcd & 1) * 8 + (j >> 3);     // 0..15
    const int m0 = mt * 256, n0 = nt * 256, S0 = nt * 64;

    const int scol = ((lane & 7) ^ (lane >> 3)) << 3;   // elems (fp32 too)
    const __hip_bfloat16* Bg = Wt + (size_t)n0 * KDIM;
    const float* xg = x     + (size_t)m0 * 1024;
    const float* hg = prevh + (size_t)m0 * 1024;
    const int arow = w * 8 + (lane >> 3);   // +p*128, +64 for hi

    auto aptr = [&](int row, int tt) -> const float* {
        return (tt < 16) ? xg + (size_t)row * 1024 + tt * 64 + scol
                         : hg + (size_t)row * 1024 + (tt - 16) * 64 + scol;
    };

    auto SB = [&](int tt, int p) {
        char* dst = lds + 65536 + (2 * (tt & 1) + p) * 16384 + w * 1024;
        const __hip_bfloat16* src =
            Bg + (size_t)(p * 128 + w * 8 + (lane >> 3)) * KDIM + tt * 64 + scol;
        gload16(src, dst);
        gload16(src + (size_t)64 * KDIM, dst + 8192);
    };

    f32x4 acc[8][4];
#pragma unroll
    for (int m = 0; m < 8; ++m)
#pragma unroll
        for (int g = 0; g < 4; ++g)
            acc[m][g] = (f32x4)0.0f;

    float4 a00a, a00b, a01a, a01b, a10a, a10b, a11a, a11b;

#define ALOAD(TT)                                                   \
    {                                                               \
        const float* q0 = aptr(arow, TT);                           \
        const float* q1 = q0 + (size_t)64 * 1024;                   \
        const float* q2 = aptr(arow + 128, TT);                     \
        const float* q3 = q2 + (size_t)64 * 1024;                   \
        a00a = *(const float4*)q0; a00b = *(const float4*)(q0 + 4); \
        a01a = *(const float4*)q1; a01b = *(const float4*)(q1 + 4); \
        a10a = *(const float4*)q2; a10b = *(const float4*)(q2 + 4); \
        a11a = *(const float4*)q3; a11b = *(const float4*)(q3 + 4); \
    }

#define AWRITE(TT)                                                  \
    {                                                               \
        char* d0 = lds + (2 * ((TT) & 1)) * 16384 + w * 1024 + lane * 16; \
        *(s16x8*)d0          = cvt8(a00a, a00b);                    \
        *(s16x8*)(d0 + 8192) = cvt8(a01a, a01b);                    \
        char* d1 = d0 + 16384;                                      \
        *(s16x8*)d1          = cvt8(a10a, a10b);                    \
        *(s16x8*)(d1 + 8192) = cvt8(a11a, a11b);                    \
    }

    // prologue: A(0) fp32 loads first (oldest), then B(0),B(1) gloads.
    ALOAD(0);
    SB(0, 0); SB(0, 1); SB(1, 0); SB(1, 1);
    asm volatile("s_waitcnt vmcnt(8)" ::: "memory");   // A(0) landed
    __builtin_amdgcn_sched_barrier(0);
    AWRITE(0);
    asm volatile("s_waitcnt vmcnt(4) lgkmcnt(0)" ::: "memory"); // SB(0)+writes
    __builtin_amdgcn_s_barrier();
    __builtin_amdgcn_sched_barrier(0);

    const int swz0 = (((lane >> 4))     ^ (lane & 7)) << 4;
    const int swz1 = (((lane >> 4) | 4) ^ (lane & 7)) << 4;
    const int brow = (wc & 1) * 64;

    s16x8 af[4][2], bf[4][2];

    for (int t = 0; t < NT; ++t) {
        const char* as = lds + (2 * (t & 1) + wr) * 16384;
        const char* bs = lds + 65536 + (2 * (t & 1) + (wc >> 1)) * 16384;

        // ---- region 1: B reads, A-lo reads, A(t+1) fp32 loads; MFMA lo ----
#pragma unroll
        for (int g = 0; g < 4; ++g) {
            bf[g][0] = *(const s16x8*)(bs + (brow + g * 16 + l15) * 128 + swz0);
            bf[g][1] = *(const s16x8*)(bs + (brow + g * 16 + l15) * 128 + swz1);
        }
#pragma unroll
        for (int m = 0; m < 4; ++m) {
            af[m][0] = *(const s16x8*)(as + (m * 16 + l15) * 128 + swz0);
            af[m][1] = *(const s16x8*)(as + (m * 16 + l15) * 128 + swz1);
        }
        if (t + 1 < NT) ALOAD(t + 1);

        __builtin_amdgcn_s_setprio(1);
#pragma unroll
        for (int kf = 0; kf < 2; ++kf)
#pragma unroll
            for (int m = 0; m < 4; ++m)
#pragma unroll
                for (int g = 0; g < 4; ++g)
                    acc[m][g] = __builtin_amdgcn_mfma_f32_16x16x32_bf16(
                        af[m][kf], bf[g][kf], acc[m][g], 0, 0, 0);
        __builtin_amdgcn_s_setprio(0);

        __builtin_amdgcn_sched_barrier(0);
        __builtin_amdgcn_s_barrier();        // mid: all B(t) reads retired
        __builtin_amdgcn_sched_barrier(0);

        // ---- region 2: A-hi reads, SB(t+2); A(t+1) cvt+write; MFMA hi ----
#pragma unroll
        for (int m = 0; m < 4; ++m) {
            af[m][0] = *(const s16x8*)(as + ((m + 4) * 16 + l15) * 128 + swz0);
            af[m][1] = *(const s16x8*)(as + ((m + 4) * 16 + l15) * 128 + swz1);
        }
        if (t + 2 < NT) { SB(t + 2, 0); SB(t + 2, 1); }

        // queue: SB(t+1)[4] + A(t+1)[8] + SB(t+2)[4] -> vmcnt(4) completes
        // SB(t+1) and A(t+1); SB(t+2) stays in flight.
        if (t + 2 < NT) {
            asm volatile("s_waitcnt vmcnt(4)" ::: "memory");
        } else if (t + 1 < NT) {
            asm volatile("s_waitcnt vmcnt(0)" ::: "memory");
        } else {
            asm volatile("s_waitcnt vmcnt(0)" ::: "memory");
        }
        __builtin_amdgcn_sched_barrier(0);
        if (t + 1 < NT) AWRITE(t + 1);   // ds_writes drain under MFMA below

        __builtin_amdgcn_s_setprio(1);
#pragma unroll
        for (int kf = 0; kf < 2; ++kf)
#pragma unroll
            for (int m = 0; m < 4; ++m)
#pragma unroll
                for (int g = 0; g < 4; ++g)
                    acc[m + 4][g] = __builtin_amdgcn_mfma_f32_16x16x32_bf16(
                        af[m][kf], bf[g][kf], acc[m + 4][g], 0, 0, 0);
        __builtin_amdgcn_s_setprio(0);

        __builtin_amdgcn_sched_barrier(0);
        asm volatile("s_waitcnt lgkmcnt(0)" ::: "memory");  // writes published
        __builtin_amdgcn_s_barrier();        // end: tile t+1 slots ready
        __builtin_amdgcn_sched_barrier(0);
    }
#undef ALOAD
#undef AWRITE

    // ---- fused epilogue: 4 gates lane-local ----
    const int st  = S0 + wc * 16 + l15;
    const float b_i = bx[st];
    const float b_f = bx[1024 + st];
    const float b_o = bx[2048 + st];
    const float b_g = bx[3072 + st];
    const int rbase = m0 + wr * 128 + (lane >> 4) * 4;

#pragma unroll
    for (int m = 0; m < 8; ++m) {
#pragma unroll
        for (int q = 0; q < 4; ++q) {
            int row = rbase + m * 16 + q;
            float ib = acc[m][0][q] + b_i;
            float fb = acc[m][1][q] + b_f;
            float ob = acc[m][2][q] + b_o;
            float gb = acc[m][3][q] + b_g;
            float ig = fast_sigmoid(ib);
            float fg = fast_sigmoid(fb);
            float og = fast_sigmoid(ob);
            float gg = fast_tanh(gb);
            float pc = prevc[(size_t)row * SDIM + st];
            float nc = pc * fg + gg * ig;
            float nh = fast_tanh(nc) * og;
            outh[(size_t)row * SDIM + st] = nh;
            outc[(size_t)row * SDIM + st] = nc;
        }
    }
}

extern "C" void kernel_launch(void* const* d_in, const int* in_sizes, int n_in,
                              void* d_out, int out_size, void* d_ws, size_t ws_size,
                              hipStream_t stream) {
    const float* x     = (const float*)d_in[0];
    const float* prevh = (const float*)d_in[1];
    const float* prevc = (const float*)d_in[2];
    const float* Wx    = (const float*)d_in[3];
    const float* bx    = (const float*)d_in[4];
    const float* Wh    = (const float*)d_in[5];

    __hip_bfloat16* Wt = (__hip_bfloat16*)d_ws;

    float* outh = (float*)d_out;
    float* outc = outh + (size_t)BATCH * SDIM;

    hipLaunchKernelGGL(convW, dim3(2048), dim3(256), 0, stream, Wx, Wh, Wt);
    hipLaunchKernelGGL(lstm_gemm, dim3(512), dim3(512), 0, stream,
                       x, prevh, Wt, bx, prevc, outh, outc);
}